// Round 1
// baseline (1100.719 us; speedup 1.0000x reference)
//
#include <hip/hip_runtime.h>
#include <hip/hip_bf16.h>
#include <math.h>

#define T_TOK 1024
#define H_DIM 2048
#define I_DIM 768
#define E_NUM 32
#define K_TOP 8

typedef __bf16 bf16x8 __attribute__((ext_vector_type(8)));
typedef float  f32x4  __attribute__((ext_vector_type(4)));

__device__ __forceinline__ bf16x8 load8_f32_bf16(const float* __restrict__ p) {
    const f32x4 a = *reinterpret_cast<const f32x4*>(p);
    const f32x4 b = *reinterpret_cast<const f32x4*>(p + 4);
    bf16x8 r;
    r[0] = (__bf16)a[0]; r[1] = (__bf16)a[1]; r[2] = (__bf16)a[2]; r[3] = (__bf16)a[3];
    r[4] = (__bf16)b[0]; r[5] = (__bf16)b[1]; r[6] = (__bf16)b[2]; r[7] = (__bf16)b[3];
    return r;
}

// ---------------- Router: logits -> top-8 -> normalized weights -------------
__global__ __launch_bounds__(256) void router_kernel(
    const float* __restrict__ x, const float* __restrict__ gw,
    float* __restrict__ wdense, unsigned int* __restrict__ masks)
{
    const int t = blockIdx.x;
    const int tid = threadIdx.x;
    __shared__ float part[256];
    __shared__ float logits[E_NUM];
    const int e = tid & 31;
    const int chunk = tid >> 5;                 // 0..7
    const float* xr = x + (size_t)t * H_DIM;
    const float* gr = gw + (size_t)e * H_DIM;
    const int base = chunk * (H_DIM / 8);       // 256 floats per chunk
    float s = 0.f;
    for (int h = 0; h < H_DIM / 8; h += 4) {
        const f32x4 xv = *reinterpret_cast<const f32x4*>(xr + base + h);
        const f32x4 gv = *reinterpret_cast<const f32x4*>(gr + base + h);
        s += xv[0]*gv[0] + xv[1]*gv[1] + xv[2]*gv[2] + xv[3]*gv[3];
    }
    part[tid] = s;
    __syncthreads();
    if (tid < E_NUM) {
        float tot = 0.f;
        for (int c = 0; c < 8; ++c) tot += part[c * 32 + tid];
        logits[tid] = tot;
    }
    __syncthreads();
    if (tid == 0) {
        float l[E_NUM];
        for (int i = 0; i < E_NUM; ++i) {
            l[i] = logits[i];
            wdense[(size_t)t * E_NUM + i] = 0.f;
        }
        unsigned mask = 0;
        int   idx[K_TOP];
        float lv[K_TOP];
        for (int k = 0; k < K_TOP; ++k) {        // top-k, ties -> lower index
            float best = -1e30f; int bi = 0;
            for (int i = 0; i < E_NUM; ++i)
                if (!((mask >> i) & 1u) && l[i] > best) { best = l[i]; bi = i; }
            mask |= (1u << bi); idx[k] = bi; lv[k] = best;
        }
        const float m = lv[0];
        float den = 0.f;
        for (int k = 0; k < K_TOP; ++k) den += expf(lv[k] - m);
        for (int k = 0; k < K_TOP; ++k)
            wdense[(size_t)t * E_NUM + idx[k]] = expf(lv[k] - m) / den;
        masks[t] = mask;
    }
}

// ---------------- Build compacted per-expert token lists --------------------
__global__ __launch_bounds__(256) void count_kernel(
    const unsigned int* __restrict__ masks, int* __restrict__ cnt)
{
    const int e = blockIdx.x;
    const int tid = threadIdx.x;
    int c = 0;
    for (int t = tid; t < T_TOK; t += 256) c += (masks[t] >> e) & 1u;
    __shared__ int red[256];
    red[tid] = c; __syncthreads();
    for (int s = 128; s > 0; s >>= 1) {
        if (tid < s) red[tid] += red[tid + s];
        __syncthreads();
    }
    if (tid == 0) cnt[e] = red[0];
}

__global__ void scan_kernel(const int* __restrict__ cnt, int* __restrict__ off)
{
    if (threadIdx.x == 0 && blockIdx.x == 0) {
        int r = 0;
        for (int e = 0; e < E_NUM; ++e) { off[e] = r; r += cnt[e]; }
    }
}

__global__ __launch_bounds__(256) void fill_kernel(
    const unsigned int* __restrict__ masks, const float* __restrict__ wdense,
    const int* __restrict__ off, int* __restrict__ tok, float* __restrict__ wgt)
{
    const int e = blockIdx.x;
    const int tid = threadIdx.x;
    const int PER = T_TOK / 256;                 // 4
    int sel[PER]; int c = 0;
    for (int i = 0; i < PER; ++i) {
        const int t = tid * PER + i;
        sel[i] = (masks[t] >> e) & 1u;
        c += sel[i];
    }
    __shared__ int s[256];
    s[tid] = c; __syncthreads();
    if (tid == 0) {                              // exclusive prefix, deterministic
        int r = 0;
        for (int j = 0; j < 256; ++j) { int v = s[j]; s[j] = r; r += v; }
    }
    __syncthreads();
    int pos = off[e] + s[tid];
    for (int i = 0; i < PER; ++i) {
        if (sel[i]) {
            const int t = tid * PER + i;
            tok[pos] = t;
            wgt[pos] = wdense[(size_t)t * E_NUM + e];
            pos++;
        }
    }
}

// ---------------- GEMM1: act = silu(x @ w13_g^T) * (x @ w13_u^T) ------------
// grid (E, I/64, T/64), block 256 (4 waves, each a 32x32 sub-tile of g and u)
__global__ __launch_bounds__(256) void gemm1_kernel(
    const float* __restrict__ x, const float* __restrict__ w13,
    const int* __restrict__ tok, const int* __restrict__ cnt,
    const int* __restrict__ off, unsigned short* __restrict__ act)
{
    const int e = blockIdx.x;
    const int c = cnt[e];
    const int m0 = blockIdx.z * 64;
    if (m0 >= c) return;
    const int o  = off[e];
    const int n0 = blockIdx.y * 64;
    const int wid  = threadIdx.x >> 6;
    const int lane = threadIdx.x & 63;
    const int wm = (wid >> 1) * 32;
    const int wn = (wid & 1) * 32;
    const int lrow = lane & 15;
    const int kgrp = (lane >> 4) * 8;

    const int r0 = m0 + wm + lrow;
    const int r1 = r0 + 16;
    const int t0 = tok[o + (r0 < c ? r0 : c - 1)];
    const int t1 = tok[o + (r1 < c ? r1 : c - 1)];
    const float* xr0 = x + (size_t)t0 * H_DIM;
    const float* xr1 = x + (size_t)t1 * H_DIM;

    const float* wbase = w13 + (size_t)e * (2 * I_DIM) * H_DIM;
    const int bcol = n0 + wn + lrow;
    const float* bg0 = wbase + (size_t)bcol * H_DIM;
    const float* bg1 = wbase + (size_t)(bcol + 16) * H_DIM;
    const float* bu0 = wbase + (size_t)(I_DIM + bcol) * H_DIM;
    const float* bu1 = wbase + (size_t)(I_DIM + bcol + 16) * H_DIM;

    f32x4 ag[2][2] = {};
    f32x4 au[2][2] = {};

    for (int k = 0; k < H_DIM; k += 32) {
        const int kk = k + kgrp;
        const bf16x8 a0 = load8_f32_bf16(xr0 + kk);
        const bf16x8 a1 = load8_f32_bf16(xr1 + kk);
        const bf16x8 g0 = load8_f32_bf16(bg0 + kk);
        const bf16x8 g1 = load8_f32_bf16(bg1 + kk);
        const bf16x8 u0 = load8_f32_bf16(bu0 + kk);
        const bf16x8 u1 = load8_f32_bf16(bu1 + kk);
        ag[0][0] = __builtin_amdgcn_mfma_f32_16x16x32_bf16(a0, g0, ag[0][0], 0, 0, 0);
        ag[0][1] = __builtin_amdgcn_mfma_f32_16x16x32_bf16(a0, g1, ag[0][1], 0, 0, 0);
        ag[1][0] = __builtin_amdgcn_mfma_f32_16x16x32_bf16(a1, g0, ag[1][0], 0, 0, 0);
        ag[1][1] = __builtin_amdgcn_mfma_f32_16x16x32_bf16(a1, g1, ag[1][1], 0, 0, 0);
        au[0][0] = __builtin_amdgcn_mfma_f32_16x16x32_bf16(a0, u0, au[0][0], 0, 0, 0);
        au[0][1] = __builtin_amdgcn_mfma_f32_16x16x32_bf16(a0, u1, au[0][1], 0, 0, 0);
        au[1][0] = __builtin_amdgcn_mfma_f32_16x16x32_bf16(a1, u0, au[1][0], 0, 0, 0);
        au[1][1] = __builtin_amdgcn_mfma_f32_16x16x32_bf16(a1, u1, au[1][1], 0, 0, 0);
    }

#pragma unroll
    for (int mi = 0; mi < 2; ++mi)
#pragma unroll
        for (int ni = 0; ni < 2; ++ni)
#pragma unroll
            for (int i = 0; i < 4; ++i) {
                const int row = m0 + wm + mi * 16 + (lane >> 4) * 4 + i;
                if (row < c) {
                    const int col = n0 + wn + ni * 16 + lrow;
                    const float g = ag[mi][ni][i];
                    const float u = au[mi][ni][i];
                    const float a = (g / (1.f + expf(-g))) * u;
                    act[(size_t)(o + row) * I_DIM + col] =
                        __builtin_bit_cast(unsigned short, (__bf16)a);
                }
            }
}

// ---------------- GEMM2: y = act @ w2^T, scatter-add weight*y into out ------
// grid (E, H/64, T/64), block 256
__global__ __launch_bounds__(256) void gemm2_kernel(
    const unsigned short* __restrict__ act, const float* __restrict__ w2,
    const int* __restrict__ tok, const float* __restrict__ wgt,
    const int* __restrict__ cnt, const int* __restrict__ off,
    float* __restrict__ out)
{
    const int e = blockIdx.x;
    const int c = cnt[e];
    const int m0 = blockIdx.z * 64;
    if (m0 >= c) return;
    const int o  = off[e];
    const int n0 = blockIdx.y * 64;
    const int wid  = threadIdx.x >> 6;
    const int lane = threadIdx.x & 63;
    const int wm = (wid >> 1) * 32;
    const int wn = (wid & 1) * 32;
    const int lrow = lane & 15;
    const int kgrp = (lane >> 4) * 8;

    const int r0 = m0 + wm + lrow;
    const int r1 = r0 + 16;
    const unsigned short* ar0 = act + (size_t)(o + (r0 < c ? r0 : c - 1)) * I_DIM;
    const unsigned short* ar1 = act + (size_t)(o + (r1 < c ? r1 : c - 1)) * I_DIM;

    const float* wbase = w2 + (size_t)e * H_DIM * I_DIM;
    const int bcol = n0 + wn + lrow;
    const float* b0 = wbase + (size_t)bcol * I_DIM;
    const float* b1 = wbase + (size_t)(bcol + 16) * I_DIM;

    f32x4 acc[2][2] = {};

    for (int k = 0; k < I_DIM; k += 32) {
        const int kk = k + kgrp;
        const bf16x8 a0 = *reinterpret_cast<const bf16x8*>(ar0 + kk);
        const bf16x8 a1 = *reinterpret_cast<const bf16x8*>(ar1 + kk);
        const bf16x8 v0 = load8_f32_bf16(b0 + kk);
        const bf16x8 v1 = load8_f32_bf16(b1 + kk);
        acc[0][0] = __builtin_amdgcn_mfma_f32_16x16x32_bf16(a0, v0, acc[0][0], 0, 0, 0);
        acc[0][1] = __builtin_amdgcn_mfma_f32_16x16x32_bf16(a0, v1, acc[0][1], 0, 0, 0);
        acc[1][0] = __builtin_amdgcn_mfma_f32_16x16x32_bf16(a1, v0, acc[1][0], 0, 0, 0);
        acc[1][1] = __builtin_amdgcn_mfma_f32_16x16x32_bf16(a1, v1, acc[1][1], 0, 0, 0);
    }

#pragma unroll
    for (int mi = 0; mi < 2; ++mi)
#pragma unroll
        for (int ni = 0; ni < 2; ++ni)
#pragma unroll
            for (int i = 0; i < 4; ++i) {
                const int row = m0 + wm + mi * 16 + (lane >> 4) * 4 + i;
                if (row < c) {
                    const int t = tok[o + row];
                    const float w = wgt[o + row];
                    const int hcol = n0 + wn + ni * 16 + lrow;
                    atomicAdd(&out[(size_t)t * H_DIM + hcol], w * acc[mi][ni][i]);
                }
            }
}

// ---------------- Launch ----------------------------------------------------
extern "C" void kernel_launch(void* const* d_in, const int* in_sizes, int n_in,
                              void* d_out, int out_size, void* d_ws, size_t ws_size,
                              hipStream_t stream)
{
    const float* x   = (const float*)d_in[0];
    const float* gw  = (const float*)d_in[1];
    const float* w13 = (const float*)d_in[2];
    const float* w2  = (const float*)d_in[3];
    float* out = (float*)d_out;

    char* ws = (char*)d_ws;
    float*          wdense = (float*)(ws + 0x00000);          // T*E f32   = 128 KB
    unsigned int*   masks  = (unsigned int*)(ws + 0x20000);   // T u32     = 4 KB
    int*            cnt    = (int*)(ws + 0x21000);            // E i32
    int*            off    = (int*)(ws + 0x22000);            // E i32
    int*            tok    = (int*)(ws + 0x23000);            // T*K i32   = 32 KB
    float*          wgt    = (float*)(ws + 0x2B000);          // T*K f32   = 32 KB
    unsigned short* act    = (unsigned short*)(ws + 0x33000); // T*K*I bf16 = 12.6 MB

    hipMemsetAsync(d_out, 0, (size_t)out_size * sizeof(float), stream);

    router_kernel<<<T_TOK, 256, 0, stream>>>(x, gw, wdense, masks);
    count_kernel<<<E_NUM, 256, 0, stream>>>(masks, cnt);
    scan_kernel<<<1, 64, 0, stream>>>(cnt, off);
    fill_kernel<<<E_NUM, 256, 0, stream>>>(masks, wdense, off, tok, wgt);
    gemm1_kernel<<<dim3(E_NUM, I_DIM / 64, T_TOK / 64), 256, 0, stream>>>(
        x, w13, tok, cnt, off, act);
    gemm2_kernel<<<dim3(E_NUM, H_DIM / 64, T_TOK / 64), 256, 0, stream>>>(
        act, w2, tok, wgt, cnt, off, out);
}

// Round 2
// 423.425 us; speedup vs baseline: 2.5996x; 2.5996x over previous
//
#include <hip/hip_runtime.h>
#include <hip/hip_bf16.h>
#include <math.h>

#define T_TOK 1024
#define H_DIM 2048
#define I_DIM 768
#define E_NUM 32
#define K_TOP 8

#define BM  128
#define BK  32
#define LDP 40   // padded LDS row length (bf16): 80B stride, 16B aligned, ~2-way banks

typedef __bf16 bf16x8 __attribute__((ext_vector_type(8)));
typedef float  f32x4  __attribute__((ext_vector_type(4)));

__device__ __forceinline__ bf16x8 cvt2_bf16(const f32x4 a, const f32x4 b) {
    bf16x8 r;
    r[0] = (__bf16)a[0]; r[1] = (__bf16)a[1]; r[2] = (__bf16)a[2]; r[3] = (__bf16)a[3];
    r[4] = (__bf16)b[0]; r[5] = (__bf16)b[1]; r[6] = (__bf16)b[2]; r[7] = (__bf16)b[3];
    return r;
}

// ---------------- Router: logits -> top-8 -> normalized weights -------------
__global__ __launch_bounds__(256) void router_kernel(
    const float* __restrict__ x, const float* __restrict__ gw,
    float* __restrict__ wdense, unsigned int* __restrict__ masks)
{
    const int t = blockIdx.x;
    const int tid = threadIdx.x;
    __shared__ float part[256];
    __shared__ float logits[E_NUM];
    const int e = tid & 31;
    const int chunk = tid >> 5;                 // 0..7
    const float* xr = x + (size_t)t * H_DIM;
    const float* gr = gw + (size_t)e * H_DIM;
    const int base = chunk * (H_DIM / 8);       // 256 floats per chunk
    float s = 0.f;
    for (int h = 0; h < H_DIM / 8; h += 4) {
        const f32x4 xv = *reinterpret_cast<const f32x4*>(xr + base + h);
        const f32x4 gv = *reinterpret_cast<const f32x4*>(gr + base + h);
        s += xv[0]*gv[0] + xv[1]*gv[1] + xv[2]*gv[2] + xv[3]*gv[3];
    }
    part[tid] = s;
    __syncthreads();
    if (tid < E_NUM) {
        float tot = 0.f;
        for (int c = 0; c < 8; ++c) tot += part[c * 32 + tid];
        logits[tid] = tot;
    }
    __syncthreads();
    if (tid == 0) {
        float l[E_NUM];
        for (int i = 0; i < E_NUM; ++i) {
            l[i] = logits[i];
            wdense[(size_t)t * E_NUM + i] = 0.f;
        }
        unsigned mask = 0;
        int   idx[K_TOP];
        float lv[K_TOP];
        for (int k = 0; k < K_TOP; ++k) {        // top-k, ties -> lower index
            float best = -1e30f; int bi = 0;
            for (int i = 0; i < E_NUM; ++i)
                if (!((mask >> i) & 1u) && l[i] > best) { best = l[i]; bi = i; }
            mask |= (1u << bi); idx[k] = bi; lv[k] = best;
        }
        const float m = lv[0];
        float den = 0.f;
        for (int k = 0; k < K_TOP; ++k) den += expf(lv[k] - m);
        for (int k = 0; k < K_TOP; ++k)
            wdense[(size_t)t * E_NUM + idx[k]] = expf(lv[k] - m) / den;
        masks[t] = mask;
    }
}

// ---------------- Build compacted per-expert token lists --------------------
__global__ __launch_bounds__(256) void count_kernel(
    const unsigned int* __restrict__ masks, int* __restrict__ cnt)
{
    const int e = blockIdx.x;
    const int tid = threadIdx.x;
    int c = 0;
    for (int t = tid; t < T_TOK; t += 256) c += (masks[t] >> e) & 1u;
    __shared__ int red[256];
    red[tid] = c; __syncthreads();
    for (int s = 128; s > 0; s >>= 1) {
        if (tid < s) red[tid] += red[tid + s];
        __syncthreads();
    }
    if (tid == 0) cnt[e] = red[0];
}

__global__ void scan_kernel(const int* __restrict__ cnt, int* __restrict__ off)
{
    if (threadIdx.x == 0 && blockIdx.x == 0) {
        int r = 0;
        for (int e = 0; e < E_NUM; ++e) { off[e] = r; r += cnt[e]; }
    }
}

__global__ __launch_bounds__(256) void fill_kernel(
    const unsigned int* __restrict__ masks, const float* __restrict__ wdense,
    const int* __restrict__ off, int* __restrict__ tok, float* __restrict__ wgt)
{
    const int e = blockIdx.x;
    const int tid = threadIdx.x;
    const int PER = T_TOK / 256;                 // 4
    int sel[PER]; int c = 0;
    for (int i = 0; i < PER; ++i) {
        const int t = tid * PER + i;
        sel[i] = (masks[t] >> e) & 1u;
        c += sel[i];
    }
    __shared__ int s[256];
    s[tid] = c; __syncthreads();
    if (tid == 0) {                              // exclusive prefix, deterministic
        int r = 0;
        for (int j = 0; j < 256; ++j) { int v = s[j]; s[j] = r; r += v; }
    }
    __syncthreads();
    int pos = off[e] + s[tid];
    for (int i = 0; i < PER; ++i) {
        if (sel[i]) {
            const int t = tid * PER + i;
            tok[pos] = t;
            wgt[pos] = wdense[(size_t)t * E_NUM + e];
            pos++;
        }
    }
}

// ---------------- GEMM1: act = silu(x @ w1^T) * (x @ w3^T) ------------------
// grid (E, I/64, T/BM), block 256. LDS double-buffered 128x32 tiles.
// Block tile: 128 tokens x 64 I-cols; B-tile = 64 gate rows + 64 up rows.
// Wave (2x2): 64 tokens x 32 I-cols -> accg[4][2] + accu[4][2].
__global__ __launch_bounds__(256) void gemm1_kernel(
    const float* __restrict__ x, const float* __restrict__ w13,
    const int* __restrict__ tok, const int* __restrict__ cnt,
    const int* __restrict__ off, unsigned short* __restrict__ act)
{
    const int e = blockIdx.x;
    const int c = cnt[e];
    const int m0 = blockIdx.z * BM;
    if (m0 >= c) return;
    const int o  = off[e];
    const int n0 = blockIdx.y * 64;
    const int tid  = threadIdx.x;
    const int wid  = tid >> 6;
    const int lane = tid & 63;
    const int wm = (wid >> 1) * 64;
    const int wn = (wid & 1) * 32;
    const int lrow = lane & 15;
    const int kgrp = (lane >> 4) * 8;

    __shared__ __align__(16) __bf16 As[2][BM][LDP];
    __shared__ __align__(16) __bf16 Bs[2][BM][LDP];

    // staging coords: 512 chunks of 8 floats; thread handles chunk tid and tid+256
    const int srow = tid >> 2;            // 0..63
    const int scol = (tid & 3) * 8;       // 0,8,16,24
    const float* xp[2];
    const float* wp[2];
    {
        int r0 = m0 + srow;       r0 = r0 < c ? r0 : c - 1;
        int r1 = m0 + srow + 64;  r1 = r1 < c ? r1 : c - 1;
        xp[0] = x + (size_t)tok[o + r0] * H_DIM + scol;
        xp[1] = x + (size_t)tok[o + r1] * H_DIM + scol;
        const float* wbase = w13 + (size_t)e * (2 * I_DIM) * H_DIM;
        wp[0] = wbase + (size_t)(n0 + srow) * H_DIM + scol;          // gate rows
        wp[1] = wbase + (size_t)(I_DIM + n0 + srow) * H_DIM + scol;  // up rows
    }

    f32x4 ra[2][2], rb[2][2];
    f32x4 accg[4][2] = {};
    f32x4 accu[4][2] = {};

    // prologue: stage 0
#pragma unroll
    for (int i = 0; i < 2; ++i) {
        ra[i][0] = *(const f32x4*)(xp[i]);
        ra[i][1] = *(const f32x4*)(xp[i] + 4);
        rb[i][0] = *(const f32x4*)(wp[i]);
        rb[i][1] = *(const f32x4*)(wp[i] + 4);
    }
#pragma unroll
    for (int i = 0; i < 2; ++i) {
        *(bf16x8*)&As[0][srow + i * 64][scol] = cvt2_bf16(ra[i][0], ra[i][1]);
        *(bf16x8*)&Bs[0][srow + i * 64][scol] = cvt2_bf16(rb[i][0], rb[i][1]);
    }
    __syncthreads();

    const int NS = H_DIM / BK;   // 64
    for (int s = 0; s < NS; ++s) {
        const int buf = s & 1;
        if (s + 1 < NS) {
            const int k = (s + 1) * BK;
#pragma unroll
            for (int i = 0; i < 2; ++i) {
                ra[i][0] = *(const f32x4*)(xp[i] + k);
                ra[i][1] = *(const f32x4*)(xp[i] + k + 4);
                rb[i][0] = *(const f32x4*)(wp[i] + k);
                rb[i][1] = *(const f32x4*)(wp[i] + k + 4);
            }
        }
        bf16x8 af[4], bg[2], bu[2];
#pragma unroll
        for (int m = 0; m < 4; ++m)
            af[m] = *(const bf16x8*)&As[buf][wm + m * 16 + lrow][kgrp];
#pragma unroll
        for (int n = 0; n < 2; ++n) {
            bg[n] = *(const bf16x8*)&Bs[buf][wn + n * 16 + lrow][kgrp];
            bu[n] = *(const bf16x8*)&Bs[buf][64 + wn + n * 16 + lrow][kgrp];
        }
#pragma unroll
        for (int m = 0; m < 4; ++m)
#pragma unroll
            for (int n = 0; n < 2; ++n) {
                accg[m][n] = __builtin_amdgcn_mfma_f32_16x16x32_bf16(af[m], bg[n], accg[m][n], 0, 0, 0);
                accu[m][n] = __builtin_amdgcn_mfma_f32_16x16x32_bf16(af[m], bu[n], accu[m][n], 0, 0, 0);
            }
        if (s + 1 < NS) {
#pragma unroll
            for (int i = 0; i < 2; ++i) {
                *(bf16x8*)&As[buf ^ 1][srow + i * 64][scol] = cvt2_bf16(ra[i][0], ra[i][1]);
                *(bf16x8*)&Bs[buf ^ 1][srow + i * 64][scol] = cvt2_bf16(rb[i][0], rb[i][1]);
            }
        }
        __syncthreads();
    }

#pragma unroll
    for (int m = 0; m < 4; ++m)
#pragma unroll
        for (int n = 0; n < 2; ++n)
#pragma unroll
            for (int i = 0; i < 4; ++i) {
                const int row = m0 + wm + m * 16 + (lane >> 4) * 4 + i;
                if (row < c) {
                    const int col = n0 + wn + n * 16 + lrow;
                    const float g = accg[m][n][i];
                    const float u = accu[m][n][i];
                    const float a = (g / (1.f + expf(-g))) * u;
                    act[(size_t)(o + row) * I_DIM + col] =
                        __builtin_bit_cast(unsigned short, (__bf16)a);
                }
            }
}

// ---------------- GEMM2: out[t] += wgt * (act @ w2^T) -----------------------
// grid (E, H/128, T/BM), block 256. Wave (2x2): 64 tokens x 64 h-cols.
__global__ __launch_bounds__(256) void gemm2_kernel(
    const unsigned short* __restrict__ act, const float* __restrict__ w2,
    const int* __restrict__ tok, const float* __restrict__ wgt,
    const int* __restrict__ cnt, const int* __restrict__ off,
    float* __restrict__ out)
{
    const int e = blockIdx.x;
    const int c = cnt[e];
    const int m0 = blockIdx.z * BM;
    if (m0 >= c) return;
    const int o  = off[e];
    const int n0 = blockIdx.y * 128;
    const int tid  = threadIdx.x;
    const int wid  = tid >> 6;
    const int lane = tid & 63;
    const int wm = (wid >> 1) * 64;
    const int wn = (wid & 1) * 64;
    const int lrow = lane & 15;
    const int kgrp = (lane >> 4) * 8;

    __shared__ __align__(16) __bf16 As[2][BM][LDP];
    __shared__ __align__(16) __bf16 Bs[2][BM][LDP];

    const int srow = tid >> 2;            // 0..63
    const int scol = (tid & 3) * 8;
    const unsigned short* ap[2];
    const float* wp[2];
    {
        int r0 = m0 + srow;       r0 = r0 < c ? r0 : c - 1;
        int r1 = m0 + srow + 64;  r1 = r1 < c ? r1 : c - 1;
        ap[0] = act + (size_t)(o + r0) * I_DIM + scol;
        ap[1] = act + (size_t)(o + r1) * I_DIM + scol;
        const float* wbase = w2 + (size_t)e * H_DIM * I_DIM;
        wp[0] = wbase + (size_t)(n0 + srow) * I_DIM + scol;
        wp[1] = wbase + (size_t)(n0 + srow + 64) * I_DIM + scol;
    }

    bf16x8 raw[2];
    f32x4 rb[2][2];
    f32x4 acc[4][4] = {};

#pragma unroll
    for (int i = 0; i < 2; ++i) {
        raw[i]   = *(const bf16x8*)(ap[i]);
        rb[i][0] = *(const f32x4*)(wp[i]);
        rb[i][1] = *(const f32x4*)(wp[i] + 4);
    }
#pragma unroll
    for (int i = 0; i < 2; ++i) {
        *(bf16x8*)&As[0][srow + i * 64][scol] = raw[i];
        *(bf16x8*)&Bs[0][srow + i * 64][scol] = cvt2_bf16(rb[i][0], rb[i][1]);
    }
    __syncthreads();

    const int NS = I_DIM / BK;   // 24
    for (int s = 0; s < NS; ++s) {
        const int buf = s & 1;
        if (s + 1 < NS) {
            const int k = (s + 1) * BK;
#pragma unroll
            for (int i = 0; i < 2; ++i) {
                raw[i]   = *(const bf16x8*)(ap[i] + k);
                rb[i][0] = *(const f32x4*)(wp[i] + k);
                rb[i][1] = *(const f32x4*)(wp[i] + k + 4);
            }
        }
        bf16x8 af[4], bf[4];
#pragma unroll
        for (int m = 0; m < 4; ++m)
            af[m] = *(const bf16x8*)&As[buf][wm + m * 16 + lrow][kgrp];
#pragma unroll
        for (int n = 0; n < 4; ++n)
            bf[n] = *(const bf16x8*)&Bs[buf][wn + n * 16 + lrow][kgrp];
#pragma unroll
        for (int m = 0; m < 4; ++m)
#pragma unroll
            for (int n = 0; n < 4; ++n)
                acc[m][n] = __builtin_amdgcn_mfma_f32_16x16x32_bf16(af[m], bf[n], acc[m][n], 0, 0, 0);
        if (s + 1 < NS) {
#pragma unroll
            for (int i = 0; i < 2; ++i) {
                *(bf16x8*)&As[buf ^ 1][srow + i * 64][scol] = raw[i];
                *(bf16x8*)&Bs[buf ^ 1][srow + i * 64][scol] = cvt2_bf16(rb[i][0], rb[i][1]);
            }
        }
        __syncthreads();
    }

#pragma unroll
    for (int m = 0; m < 4; ++m)
#pragma unroll
        for (int n = 0; n < 4; ++n)
#pragma unroll
            for (int i = 0; i < 4; ++i) {
                const int row = m0 + wm + m * 16 + (lane >> 4) * 4 + i;
                if (row < c) {
                    const int t = tok[o + row];
                    const float w = wgt[o + row];
                    const int hcol = n0 + wn + n * 16 + lrow;
                    atomicAdd(&out[(size_t)t * H_DIM + hcol], w * acc[m][n][i]);
                }
            }
}

// ---------------- Launch ----------------------------------------------------
extern "C" void kernel_launch(void* const* d_in, const int* in_sizes, int n_in,
                              void* d_out, int out_size, void* d_ws, size_t ws_size,
                              hipStream_t stream)
{
    const float* x   = (const float*)d_in[0];
    const float* gw  = (const float*)d_in[1];
    const float* w13 = (const float*)d_in[2];
    const float* w2  = (const float*)d_in[3];
    float* out = (float*)d_out;

    char* ws = (char*)d_ws;
    float*          wdense = (float*)(ws + 0x00000);          // T*E f32   = 128 KB
    unsigned int*   masks  = (unsigned int*)(ws + 0x20000);   // T u32     = 4 KB
    int*            cnt    = (int*)(ws + 0x21000);            // E i32
    int*            off    = (int*)(ws + 0x22000);            // E i32
    int*            tok    = (int*)(ws + 0x23000);            // T*K i32   = 32 KB
    float*          wgt    = (float*)(ws + 0x2B000);          // T*K f32   = 32 KB
    unsigned short* act    = (unsigned short*)(ws + 0x33000); // T*K*I bf16 = 12.6 MB

    hipMemsetAsync(d_out, 0, (size_t)out_size * sizeof(float), stream);

    router_kernel<<<T_TOK, 256, 0, stream>>>(x, gw, wdense, masks);
    count_kernel<<<E_NUM, 256, 0, stream>>>(masks, cnt);
    scan_kernel<<<1, 64, 0, stream>>>(cnt, off);
    fill_kernel<<<E_NUM, 256, 0, stream>>>(masks, wdense, off, tok, wgt);
    gemm1_kernel<<<dim3(E_NUM, I_DIM / 64, (T_TOK + BM - 1) / BM), 256, 0, stream>>>(
        x, w13, tok, cnt, off, act);
    gemm2_kernel<<<dim3(E_NUM, H_DIM / 128, (T_TOK + BM - 1) / BM), 256, 0, stream>>>(
        act, w2, tok, wgt, cnt, off, out);
}